// Round 1
// baseline (229.112 us; speedup 1.0000x reference)
//
#include <hip/hip_runtime.h>
#include <math.h>

#define BB 4096
#define PP 512
#define WDT 10

__device__ __forceinline__ float fast_tanh(float x) {
    // tanh(x) = 1 - 2/(e^{2x}+1); clamp so e^{2x} can't overflow
    x = fminf(fmaxf(x, -15.0f), 15.0f);
    float e = __expf(2.0f * x);                 // v_exp_f32 path
    float r = __builtin_amdgcn_rcpf(e + 1.0f);  // fast v_rcp_f32
    return 1.0f - 2.0f * r;
}

__global__ __launch_bounds__(256) void frc_2b_kernel(
    const float* __restrict__ invar,    // [B,P,5]
    const float* __restrict__ vectors,  // [B,P,9]
    const float* __restrict__ w1_0,     // [5,10]
    const float* __restrict__ b1_0,     // [10]
    const float* __restrict__ w1_1,     // [10,10]
    const float* __restrict__ b1_1,     // [10]
    const float* __restrict__ lin0_w,   // [3,10]
    const float* __restrict__ na0_b,    // [10]
    const float* __restrict__ lin1_w,   // [10,10]
    const float* __restrict__ na1_b,    // [10]
    const float* __restrict__ final_w,  // [10,1]
    float* __restrict__ out)            // [B,3]
{
    const int b   = blockIdx.x;
    const int tid = threadIdx.x;

    float acc0 = 0.f, acc1 = 0.f, acc2 = 0.f;

    #pragma unroll
    for (int pp = 0; pp < 2; ++pp) {
        const int p = tid + pp * 256;
        const float* iv = invar   + ((size_t)b * PP + p) * 5;
        const float* vv = vectors + ((size_t)b * PP + p) * 9;

        // ---------------- scalar branch: Linear(5,10)+ReLU, Linear(10,10)+ReLU
        float in5[5];
        #pragma unroll
        for (int i = 0; i < 5; ++i) in5[i] = iv[i];

        float y[WDT];
        #pragma unroll
        for (int j = 0; j < WDT; ++j) {
            float a = b1_0[j];
            #pragma unroll
            for (int i = 0; i < 5; ++i) a = fmaf(in5[i], w1_0[i * WDT + j], a);
            y[j] = fmaxf(a, 0.f);
        }
        float y2[WDT];
        #pragma unroll
        for (int j = 0; j < WDT; ++j) {
            float a = b1_1[j];
            #pragma unroll
            for (int i = 0; i < WDT; ++i) a = fmaf(y[i], w1_1[i * WDT + j], a);
            y2[j] = fmaxf(a, 0.f);
        }

        // ---------------- equivariant branch
        float v[9];
        #pragma unroll
        for (int i = 0; i < 9; ++i) v[i] = vv[i];

        const float inv_sqrt3  = 0.57735026918962576f;
        const float inv_sqrt10 = 0.31622776601683794f;

        // self_intrc #1: 3x1o -> 10x1o, NormActivation(tanh)
        float x0[WDT][3];
        #pragma unroll
        for (int w = 0; w < WDT; ++w) {
            float c0 = 0.f, c1 = 0.f, c2 = 0.f;
            #pragma unroll
            for (int u = 0; u < 3; ++u) {
                float wt = lin0_w[u * WDT + w];
                c0 = fmaf(v[u * 3 + 0], wt, c0);
                c1 = fmaf(v[u * 3 + 1], wt, c1);
                c2 = fmaf(v[u * 3 + 2], wt, c2);
            }
            c0 *= inv_sqrt3; c1 *= inv_sqrt3; c2 *= inv_sqrt3;
            float n2    = fmaxf(c0 * c0 + c1 * c1 + c2 * c2, 1e-12f);
            float inv_n = rsqrtf(n2);
            float n     = n2 * inv_n;            // sqrt(n2)
            float s     = fast_tanh(n + na0_b[w]) * inv_n;
            x0[w][0] = c0 * s; x0[w][1] = c1 * s; x0[w][2] = c2 * s;
        }

        // self_intrc #2: 10x1o -> 10x1o, NormActivation(tanh),
        // then elementwise gate by y2 and final o3.Linear 10x1o -> 1x1o
        float o0 = 0.f, o1 = 0.f, o2 = 0.f;
        #pragma unroll
        for (int w = 0; w < WDT; ++w) {
            float c0 = 0.f, c1 = 0.f, c2 = 0.f;
            #pragma unroll
            for (int u = 0; u < WDT; ++u) {
                float wt = lin1_w[u * WDT + w];
                c0 = fmaf(x0[u][0], wt, c0);
                c1 = fmaf(x0[u][1], wt, c1);
                c2 = fmaf(x0[u][2], wt, c2);
            }
            c0 *= inv_sqrt10; c1 *= inv_sqrt10; c2 *= inv_sqrt10;
            float n2    = fmaxf(c0 * c0 + c1 * c1 + c2 * c2, 1e-12f);
            float inv_n = rsqrtf(n2);
            float n     = n2 * inv_n;
            float s     = fast_tanh(n + na1_b[w]) * inv_n;
            // gate * final weight * 1/sqrt(10)
            float g = y2[w] * s * final_w[w] * inv_sqrt10;
            o0 = fmaf(c0, g, o0);
            o1 = fmaf(c1, g, o1);
            o2 = fmaf(c2, g, o2);
        }
        acc0 += o0; acc1 += o1; acc2 += o2;
    }

    // ---------------- block reduction over the 512 pairs of this batch row
    #pragma unroll
    for (int off = 32; off > 0; off >>= 1) {
        acc0 += __shfl_down(acc0, off, 64);
        acc1 += __shfl_down(acc1, off, 64);
        acc2 += __shfl_down(acc2, off, 64);
    }
    __shared__ float red[4][3];
    const int wave = tid >> 6;
    const int lane = tid & 63;
    if (lane == 0) { red[wave][0] = acc0; red[wave][1] = acc1; red[wave][2] = acc2; }
    __syncthreads();
    if (tid == 0) {
        float r0 = 0.f, r1 = 0.f, r2 = 0.f;
        #pragma unroll
        for (int wv = 0; wv < 4; ++wv) { r0 += red[wv][0]; r1 += red[wv][1]; r2 += red[wv][2]; }
        out[b * 3 + 0] = r0;
        out[b * 3 + 1] = r1;
        out[b * 3 + 2] = r2;
    }
}

extern "C" void kernel_launch(void* const* d_in, const int* in_sizes, int n_in,
                              void* d_out, int out_size, void* d_ws, size_t ws_size,
                              hipStream_t stream) {
    const float* invar   = (const float*)d_in[0];
    const float* vectors = (const float*)d_in[1];
    const float* w1_0    = (const float*)d_in[2];
    const float* b1_0    = (const float*)d_in[3];
    const float* w1_1    = (const float*)d_in[4];
    const float* b1_1    = (const float*)d_in[5];
    const float* lin0_w  = (const float*)d_in[6];
    const float* na0_b   = (const float*)d_in[7];
    const float* lin1_w  = (const float*)d_in[8];
    const float* na1_b   = (const float*)d_in[9];
    const float* final_w = (const float*)d_in[10];
    float* out = (float*)d_out;

    frc_2b_kernel<<<BB, 256, 0, stream>>>(invar, vectors, w1_0, b1_0, w1_1, b1_1,
                                          lin0_w, na0_b, lin1_w, na1_b, final_w, out);
}

// Round 3
// 219.987 us; speedup vs baseline: 1.0415x; 1.0415x over previous
//
#include <hip/hip_runtime.h>
#include <math.h>

#define BB 4096
#define PP 512
#define WDT 10

// tanh(x) = 1 - 2/(exp2(2*log2e*x)+1). Inf-safe without clamps:
// x->+inf: exp2->inf, rcp->0, result 1;  x->-inf: exp2->0, result -1.
__device__ __forceinline__ float fast_tanh(float x) {
    float e = __builtin_amdgcn_exp2f(x * 2.8853900817779268f); // v_exp_f32
    return 1.0f - 2.0f * __builtin_amdgcn_rcpf(e + 1.0f);      // v_rcp_f32
}

__global__ __launch_bounds__(256, 2) void frc_2b_kernel(
    const float* __restrict__ invar,    // [B,P,5]
    const float* __restrict__ vectors,  // [B,P,9]
    const float* __restrict__ w1_0,     // [5,10]
    const float* __restrict__ b1_0,     // [10]
    const float* __restrict__ w1_1,     // [10,10]
    const float* __restrict__ b1_1,     // [10]
    const float* __restrict__ lin0_w,   // [3,10]
    const float* __restrict__ na0_b,    // [10]
    const float* __restrict__ lin1_w,   // [10,10]
    const float* __restrict__ na1_b,    // [10]
    const float* __restrict__ final_w,  // [10,1]
    float* __restrict__ out)            // [B,3]
{
    const int b   = blockIdx.x;
    const int tid = threadIdx.x;

    const float k3sq   = 0.33333333333333333f;  // (1/sqrt(3))^2
    const float k3k10  = 0.18257418583505536f;  // 1/sqrt(30)
    const float k10    = 0.31622776601683794f;  // 1/sqrt(10)

    // hoisted final_w * 1/sqrt(10)
    float fwk[WDT];
    #pragma unroll
    for (int w = 0; w < WDT; ++w) fwk[w] = final_w[w] * k10;

    float acc0 = 0.f, acc1 = 0.f, acc2 = 0.f;

    #pragma unroll
    for (int pp = 0; pp < 2; ++pp) {
        const int p = tid + pp * 256;
        const float* iv = invar   + ((size_t)b * PP + p) * 5;
        const float* vv = vectors + ((size_t)b * PP + p) * 9;

        // ---------------- scalar branch: Linear(5,10)+ReLU, Linear(10,10)+ReLU
        float in5[5];
        #pragma unroll
        for (int i = 0; i < 5; ++i) in5[i] = iv[i];

        float y[WDT];
        #pragma unroll
        for (int j = 0; j < WDT; ++j) {
            float a = b1_0[j];
            #pragma unroll
            for (int i = 0; i < 5; ++i) a = fmaf(in5[i], w1_0[i * WDT + j], a);
            y[j] = fmaxf(a, 0.f);
        }
        float y2[WDT];
        #pragma unroll
        for (int j = 0; j < WDT; ++j) {
            float a = b1_1[j];
            #pragma unroll
            for (int i = 0; i < WDT; ++i) a = fmaf(y[i], w1_1[i * WDT + j], a);
            y2[j] = fmaxf(a, 0.f);
        }

        // ---------------- equivariant branch
        float v[9];
        #pragma unroll
        for (int i = 0; i < 9; ++i) v[i] = vv[i];

        // self_intrc #1: 3x1o -> 10x1o, NormActivation(tanh).
        // x0 stored with 1/sqrt(30) = (1/sqrt3)*(1/sqrt10) folded in, so the
        // next linear's outputs come out exactly as reference y2v.
        float x0[WDT][3];
        #pragma unroll
        for (int w = 0; w < WDT; ++w) {
            float c0 = 0.f, c1 = 0.f, c2 = 0.f;
            #pragma unroll
            for (int u = 0; u < 3; ++u) {
                float wt = lin0_w[u * WDT + w];
                c0 = fmaf(v[u * 3 + 0], wt, c0);
                c1 = fmaf(v[u * 3 + 1], wt, c1);
                c2 = fmaf(v[u * 3 + 2], wt, c2);
            }
            float n2u   = fmaf(c0, c0, fmaf(c1, c1, c2 * c2));
            float m     = fmaxf(n2u * k3sq, 1e-12f);   // = ||y1||^2, clamped
            float inv_n = __builtin_amdgcn_rsqf(m);
            float n     = m * inv_n;                   // sqrt(m)
            float t     = fast_tanh(n + na0_b[w]);
            float f     = t * inv_n * k3k10;
            x0[w][0] = c0 * f; x0[w][1] = c1 * f; x0[w][2] = c2 * f;
        }

        // self_intrc #2 + elementwise gate + final linear, fused.
        float o0 = 0.f, o1 = 0.f, o2 = 0.f;
        #pragma unroll
        for (int w = 0; w < WDT; ++w) {
            float c0 = 0.f, c1 = 0.f, c2 = 0.f;
            #pragma unroll
            for (int u = 0; u < WDT; ++u) {
                float wt = lin1_w[u * WDT + w];
                c0 = fmaf(x0[u][0], wt, c0);
                c1 = fmaf(x0[u][1], wt, c1);
                c2 = fmaf(x0[u][2], wt, c2);
            }
            // c == reference y2v (scales folded upstream)
            float m     = fmaxf(fmaf(c0, c0, fmaf(c1, c1, c2 * c2)), 1e-12f);
            float inv_n = __builtin_amdgcn_rsqf(m);
            float n     = m * inv_n;
            float t     = fast_tanh(n + na1_b[w]);
            float g     = y2[w] * t * inv_n * fwk[w];
            o0 = fmaf(c0, g, o0);
            o1 = fmaf(c1, g, o1);
            o2 = fmaf(c2, g, o2);
        }
        acc0 += o0; acc1 += o1; acc2 += o2;
    }

    // ---------------- block reduction over the 512 pairs of this batch row
    #pragma unroll
    for (int off = 32; off > 0; off >>= 1) {
        acc0 += __shfl_down(acc0, off, 64);
        acc1 += __shfl_down(acc1, off, 64);
        acc2 += __shfl_down(acc2, off, 64);
    }
    __shared__ float red[4][3];
    const int wave = tid >> 6;
    const int lane = tid & 63;
    if (lane == 0) { red[wave][0] = acc0; red[wave][1] = acc1; red[wave][2] = acc2; }
    __syncthreads();
    if (tid == 0) {
        float r0 = 0.f, r1 = 0.f, r2 = 0.f;
        #pragma unroll
        for (int wv = 0; wv < 4; ++wv) { r0 += red[wv][0]; r1 += red[wv][1]; r2 += red[wv][2]; }
        out[b * 3 + 0] = r0;
        out[b * 3 + 1] = r1;
        out[b * 3 + 2] = r2;
    }
}

extern "C" void kernel_launch(void* const* d_in, const int* in_sizes, int n_in,
                              void* d_out, int out_size, void* d_ws, size_t ws_size,
                              hipStream_t stream) {
    const float* invar   = (const float*)d_in[0];
    const float* vectors = (const float*)d_in[1];
    const float* w1_0    = (const float*)d_in[2];
    const float* b1_0    = (const float*)d_in[3];
    const float* w1_1    = (const float*)d_in[4];
    const float* b1_1    = (const float*)d_in[5];
    const float* lin0_w  = (const float*)d_in[6];
    const float* na0_b   = (const float*)d_in[7];
    const float* lin1_w  = (const float*)d_in[8];
    const float* na1_b   = (const float*)d_in[9];
    const float* final_w = (const float*)d_in[10];
    float* out = (float*)d_out;

    frc_2b_kernel<<<BB, 256, 0, stream>>>(invar, vectors, w1_0, b1_0, w1_1, b1_1,
                                          lin0_w, na0_b, lin1_w, na1_b, final_w, out);
}